// Round 1
// baseline (443.986 us; speedup 1.0000x reference)
//
#include <hip/hip_runtime.h>
#include <hip/hip_bf16.h>

#define N_NODES 100000
#define N_EDGES 1600000
#define NBUCKET 391                 // ceil(100000 / 256) coarse buckets (dst >> 8)
#define NBLK 640                    // edge chunks (~2.5 blocks/CU)
#define CHUNK_E 2500                // 640 * 2500 = 1.6M exactly (div by 4 for int4)
#define T2 (NBUCKET * NBLK)         // 250240
#define NCH2 ((T2 + 511) / 512)     // 489 (<= 512 for single-block scan_off)

typedef short v8s __attribute__((ext_vector_type(8)));
typedef float v4f __attribute__((ext_vector_type(4)));

static __device__ __forceinline__ unsigned pack_bf2(float a, float b) {
    __hip_bfloat162 p = __float22bfloat162_rn(make_float2(a, b));
    return *reinterpret_cast<unsigned*>(&p);
}
static __device__ __forceinline__ float2 bf2_to_f2(unsigned u) {
    __hip_bfloat162 p = *reinterpret_cast<__hip_bfloat162*>(&u);
    return __bfloat1622float2(p);
}

// ---------- S1 + prep: coarse histogram (blocks 0..NBLK-1) + W transpose (block NBLK) ----------
__global__ __launch_bounds__(256) void s1_hist_prep(const int* __restrict__ dst,
                                                    int* __restrict__ bh,
                                                    const float* __restrict__ W1,
                                                    const float* __restrict__ W2,
                                                    short* __restrict__ wt1,   // [64][128]
                                                    short* __restrict__ wt2) { // [64][64]
    const int t = threadIdx.x;
    if (blockIdx.x == NBLK) {
        for (int i = t; i < 64 * 128; i += 256) {
            const int c = i >> 7, k = i & 127;
            wt1[i] = (short)(pack_bf2(W1[k * 64 + c], 0.f) & 0xFFFF);
        }
        for (int i = t; i < 64 * 64; i += 256) {
            const int c = i >> 6, k = i & 63;
            wt2[i] = (short)(pack_bf2(W2[k * 64 + c], 0.f) & 0xFFFF);
        }
        return;
    }
    __shared__ int hist[NBUCKET];
    for (int i = t; i < NBUCKET; i += 256) hist[i] = 0;
    __syncthreads();
    const int4* d4 = (const int4*)(dst + blockIdx.x * CHUNK_E);
    for (int i = t; i < CHUNK_E / 4; i += 256) {
        const int4 v = d4[i];
        atomicAdd(&hist[v.x >> 8], 1);
        atomicAdd(&hist[v.y >> 8], 1);
        atomicAdd(&hist[v.z >> 8], 1);
        atomicAdd(&hist[v.w >> 8], 1);
    }
    __syncthreads();
    for (int i = t; i < NBUCKET; i += 256)
        bh[i * NBLK + blockIdx.x] = hist[i];
}

// ---------- MFMA GEMM: out slice-major bf16 [4][N][16cols] = in[M,K] @ W[K,64] ----------
// IN_SLICED: input is bf16 in slice-major [4][N][16] layout (layer-2 h1).
template<int K, bool IN_SLICED>
__global__ __launch_bounds__(256) void gemm_mfma(const void* __restrict__ in,
                                                 const short* __restrict__ wt,  // [64][K] bf16
                                                 unsigned* __restrict__ outp) { // [4][N][8] bf162
    __shared__ unsigned xs[64][K / 2 + 4];
    __shared__ unsigned ws[64][K / 2 + 4];
    const int t = threadIdx.x;
    const int row0 = blockIdx.x * 64;
    {
        const uint2* g = (const uint2*)wt;
        for (int i = t; i < 64 * K / 4; i += 256) {
            const int r = i / (K / 4), cu = i % (K / 4);
            ((uint2*)&ws[r][0])[cu] = g[i];
        }
    }
    if (IN_SLICED) {
        const uint2* g = (const uint2*)in;
        for (int i = t; i < 64 * K / 4; i += 256) {
            const int r = i / (K / 4), cu = i % (K / 4);  // cu in [0,16): 8B chunk, cols 4cu..4cu+3
            const int row = row0 + r;
            uint2 v = make_uint2(0u, 0u);
            // slice p = cu>>2 (16 cols), within-slice uint2 chunk = cu&3
            if (row < N_NODES) v = g[((size_t)(cu >> 2) * N_NODES + row) * 4 + (cu & 3)];
            ((uint2*)&xs[r][0])[cu] = v;
        }
    } else {
        const float4* g = (const float4*)in;
        for (int i = t; i < 64 * K / 4; i += 256) {
            const int r = i / (K / 4), cu = i % (K / 4);
            const int row = row0 + r;
            uint2 v = make_uint2(0u, 0u);
            if (row < N_NODES) {
                float4 f = g[(size_t)row * (K / 4) + cu];
                v.x = pack_bf2(f.x, f.y);
                v.y = pack_bf2(f.z, f.w);
            }
            ((uint2*)&xs[r][0])[cu] = v;
        }
    }
    __syncthreads();
    const int w = t >> 6;
    const int lane = t & 63;
    const int l15 = lane & 15;
    const int quad = lane >> 4;
    v4f acc[4];
#pragma unroll
    for (int tt = 0; tt < 4; ++tt) acc[tt] = (v4f){0.f, 0.f, 0.f, 0.f};
#pragma unroll
    for (int k0 = 0; k0 < K; k0 += 32) {
        const int ku = k0 / 2 + quad * 4;
        const v8s xb = *(const v8s*)&xs[w * 16 + l15][ku];   // B: n=node
#pragma unroll
        for (int tt = 0; tt < 4; ++tt) {
            const v8s wa = *(const v8s*)&ws[16 * tt + l15][ku];  // A: m=out col
            acc[tt] = __builtin_amdgcn_mfma_f32_16x16x32_bf16(wa, xb, acc[tt], 0, 0, 0);
        }
    }
    const int node = row0 + w * 16 + l15;
    if (node < N_NODES) {
        // acc[tt][j] = out col 16*tt + 4*quad + j  ->  slice tt, within-slice col 4*quad+j
#pragma unroll
        for (int tt = 0; tt < 4; ++tt) {
            uint2 o;
            o.x = pack_bf2(acc[tt][0], acc[tt][1]);
            o.y = pack_bf2(acc[tt][2], acc[tt][3]);
            *(uint2*)&outp[((size_t)tt * N_NODES + node) * 8 + 2 * quad] = o;
        }
    }
}

// ---------- S2: 3-phase exclusive scan of bh[T2] -> bh_ex ----------
__global__ __launch_bounds__(256) void scan_sums(const int* __restrict__ v,
                                                 int* __restrict__ csum, int n) {
    __shared__ int red[256];
    const int t = threadIdx.x;
    const int i0 = blockIdx.x * 512 + 2 * t;
    int a = (i0 < n) ? v[i0] : 0;
    int b = (i0 + 1 < n) ? v[i0 + 1] : 0;
    red[t] = a + b;
    __syncthreads();
    for (int off = 128; off > 0; off >>= 1) {
        if (t < off) red[t] += red[t + off];
        __syncthreads();
    }
    if (t == 0) csum[blockIdx.x] = red[0];
}

__global__ __launch_bounds__(512) void scan_off(const int* __restrict__ csum,
                                                int* __restrict__ coff, int nch) {
    __shared__ int part[512];
    const int t = threadIdx.x;
    int v = (t < nch) ? csum[t] : 0;
    part[t] = v;
    __syncthreads();
    for (int off = 1; off < 512; off <<= 1) {
        int u = (t >= off) ? part[t - off] : 0;
        __syncthreads();
        part[t] += u;
        __syncthreads();
    }
    if (t < nch) coff[t] = part[t] - v;   // exclusive
}

__global__ __launch_bounds__(256) void scan_apply(const int* __restrict__ v,
                                                  const int* __restrict__ coff,
                                                  int* __restrict__ vex, int n) {
    __shared__ int part[256];
    const int t = threadIdx.x;
    const int i0 = blockIdx.x * 512 + 2 * t;
    int a = (i0 < n) ? v[i0] : 0;
    int b = (i0 + 1 < n) ? v[i0 + 1] : 0;
    int pair = a + b;
    part[t] = pair;
    __syncthreads();
    for (int off = 1; off < 256; off <<= 1) {
        int u = (t >= off) ? part[t - off] : 0;
        __syncthreads();
        part[t] += u;
        __syncthreads();
    }
    const int e0 = coff[blockIdx.x] + part[t] - pair;
    if (i0 < n)     vex[i0] = e0;
    if (i0 + 1 < n) vex[i0 + 1] = e0 + a;
}

// ---------- S3: scatter edges into coarse buckets (int4/float4 reads) ----------
__global__ __launch_bounds__(256) void s3_scatter(const int* __restrict__ src,
                                                  const int* __restrict__ dst,
                                                  const float* __restrict__ w,
                                                  const int* __restrict__ bh_ex,
                                                  int2* __restrict__ coarse) {
    __shared__ int cur[NBUCKET];
    const int t = threadIdx.x;
    for (int i = t; i < NBUCKET; i += 256) cur[i] = bh_ex[i * NBLK + blockIdx.x];
    __syncthreads();
    const int e0 = blockIdx.x * CHUNK_E;
    const int4*   s4 = (const int4*)(src + e0);
    const int4*   d4 = (const int4*)(dst + e0);
    const float4* w4 = (const float4*)(w + e0);
    for (int i = t; i < CHUNK_E / 4; i += 256) {
        const int4 sv = s4[i];
        const int4 dv = d4[i];
        const float4 wv = w4[i];
        {
            const int pos = atomicAdd(&cur[dv.x >> 8], 1);
            coarse[pos] = make_int2(sv.x | ((dv.x & 255) << 17), __float_as_int(wv.x));
        }
        {
            const int pos = atomicAdd(&cur[dv.y >> 8], 1);
            coarse[pos] = make_int2(sv.y | ((dv.y & 255) << 17), __float_as_int(wv.y));
        }
        {
            const int pos = atomicAdd(&cur[dv.z >> 8], 1);
            coarse[pos] = make_int2(sv.z | ((dv.z & 255) << 17), __float_as_int(wv.z));
        }
        {
            const int pos = atomicAdd(&cur[dv.w >> 8], 1);
            coarse[pos] = make_int2(sv.w | ((dv.w & 255) << 17), __float_as_int(wv.w));
        }
    }
}

// ---------- S4: per-bucket fine sort (256 nodes, 1 bin/thread) + row_ptr ----------
// record = src(17 bits) | wq(15 bits, w*32767 fixed point)
__global__ __launch_bounds__(256) void s4_fine(const int2* __restrict__ coarse,
                                               const int* __restrict__ bh_ex,
                                               unsigned* __restrict__ edge_sorted,
                                               int* __restrict__ row_ptr) {
    __shared__ int hist[256];
    __shared__ int part[256];
    __shared__ int cursor[256];
    const int b = blockIdx.x;
    const int t = threadIdx.x;
    const int beg = bh_ex[b * NBLK];
    const int end = (b + 1 < NBUCKET) ? bh_ex[(b + 1) * NBLK] : N_EDGES;
    hist[t] = 0;
    __syncthreads();
    for (int i = beg + t; i < end; i += 256)
        atomicAdd(&hist[(coarse[i].x >> 17) & 255], 1);
    __syncthreads();
    const int v = hist[t];
    part[t] = v;
    __syncthreads();
    for (int off = 1; off < 256; off <<= 1) {
        int u = (t >= off) ? part[t - off] : 0;
        __syncthreads();
        part[t] += u;
        __syncthreads();
    }
    const int excl = beg + part[t] - v;
    cursor[t] = excl;
    const int node = b * 256 + t;
    if (node < N_NODES) row_ptr[node] = excl;
    if (b == NBUCKET - 1 && t == 0) row_ptr[N_NODES] = N_EDGES;
    __syncthreads();
    for (int i = beg + t; i < end; i += 256) {
        const int2 ev = coarse[i];
        const int f = (ev.x >> 17) & 255;
        const int pos = atomicAdd(&cursor[f], 1);
        unsigned wq = (unsigned)__float2uint_rn(__int_as_float(ev.y) * 32767.f);
        wq = min(wq, 32767u);
        edge_sorted[pos] = (unsigned)(ev.x & 0x1FFFF) | (wq << 17);
    }
}

// ---------- Gather step (sliced): 16 edges, 4 lanes/edge, per-lane 8B slice load ----------
template<bool FULL>
static __device__ __forceinline__ void quad_step(const unsigned* __restrict__ hs,
                                                 const unsigned* __restrict__ recs,
                                                 int e, int n, int eq, int cg,
                                                 float acc[4]) {
    unsigned u;
    if (FULL) {
        u = __builtin_nontemporal_load(&recs[e + eq]);
    } else {
        u = __builtin_nontemporal_load(&recs[e + min(eq, n - 1)]);
    }
    const int sx = u & 0x1FFFF;
    float wq = (float)(u >> 17) * (1.f / 32767.f);
    if (!FULL) wq = (eq < n) ? wq : 0.f;
    const uint2 hv = *(const uint2*)&hs[(size_t)sx * 8 + cg * 2];
    const float2 f0 = bf2_to_f2(hv.x);
    const float2 f1 = bf2_to_f2(hv.y);
    acc[0] += wq * f0.x; acc[1] += wq * f0.y;
    acc[2] += wq * f1.x; acc[3] += wq * f1.y;
}

// ---------- Gather-aggregate, one 16-col slice (3.2 MB -> per-XCD L2 resident) ----------
// wave per node; 4 lanes/edge (8B each), 16 edges per step (== avg degree).
// Epilogue: butterfly-with-rotation over edge lanes; lanes 0..15 store 16 cols.
template<bool OUT_BF>
__global__ __launch_bounds__(256) void gather_pass(const unsigned* __restrict__ hs, // slice [N][8] bf162
                                                   const int* __restrict__ row_ptr,
                                                   const unsigned* __restrict__ recs,
                                                   const float* __restrict__ bias,
                                                   void* __restrict__ outp,
                                                   int p) {
    const int node = (blockIdx.x * 256 + threadIdx.x) >> 6;
    if (node >= N_NODES) return;
    const int lane = threadIdx.x & 63;
    const int eq = lane >> 2;        // which of 16 edges
    const int cg = lane & 3;         // 8B chunk: within-slice cols 4cg..4cg+3
    const int beg = __builtin_amdgcn_readfirstlane(row_ptr[node]);
    const int end = __builtin_amdgcn_readfirstlane(row_ptr[node + 1]);
    float acc[4];
#pragma unroll
    for (int i = 0; i < 4; ++i) acc[i] = 0.f;
    int e = beg;
    for (; e + 32 <= end; e += 32) {          // 2 independent chains in flight
        quad_step<true>(hs, recs, e, 16, eq, cg, acc);
        quad_step<true>(hs, recs, e + 16, 16, eq, cg, acc);
    }
    if (e + 16 <= end) {
        quad_step<true>(hs, recs, e, 16, eq, cg, acc);
        e += 16;
    }
    if (e < end) {
        quad_step<false>(hs, recs, e, end - e, eq, cg, acc);
    }
    // stage 1: xor 4 (eq bit0) — keep upper 2 accs if lane&4
    const bool h4 = (lane & 4) != 0;
    const float t0 = __shfl_xor(h4 ? acc[0] : acc[2], 4);
    const float t1 = __shfl_xor(h4 ? acc[1] : acc[3], 4);
    const float a0 = (h4 ? acc[2] : acc[0]) + t0;
    const float a1 = (h4 ? acc[3] : acc[1]) + t1;
    // stage 2: xor 8 (eq bit1) — keep upper if lane&8
    const bool h8 = (lane & 8) != 0;
    const float u0 = __shfl_xor(h8 ? a0 : a1, 8);
    float b0 = (h8 ? a1 : a0) + u0;
    // stages 3/4: plain sums over eq bits 2,3 (col identical across these lanes)
    b0 += __shfl_xor(b0, 16);
    b0 += __shfl_xor(b0, 32);
    if (lane < 16) {
        const int col = 4 * cg + (h4 ? 2 : 0) + (h8 ? 1 : 0); // within-slice col
        const float r = fmaxf(b0 + bias[p * 16 + col], 0.f);
        if (OUT_BF) {
            const unsigned pk = pack_bf2(r, 0.f);
            __builtin_nontemporal_store((short)(pk & 0xFFFF),
                &((short*)outp)[((size_t)p * N_NODES + node) * 16 + col]);
        } else {
            __builtin_nontemporal_store(r,
                &((float*)outp)[(size_t)node * 64 + p * 16 + col]);
        }
    }
}

extern "C" void kernel_launch(void* const* d_in, const int* in_sizes, int n_in,
                              void* d_out, int out_size, void* d_ws, size_t ws_size,
                              hipStream_t stream) {
    const float* x    = (const float*)d_in[0];          // [100000, 128]
    const int*   eidx = (const int*)d_in[1];            // [2, 1600000]
    const float* mask = (const float*)d_in[2];          // [1600000]
    const float* W1   = (const float*)d_in[3];          // [128, 64]
    const float* b1   = (const float*)d_in[4];          // [64]
    const float* W2   = (const float*)d_in[5];          // [64, 64]
    const float* b2   = (const float*)d_in[6];          // [64]
    float* out = (float*)d_out;                          // [100000, 64]

    const int* src = eidx;
    const int* dst = eidx + N_EDGES;

    // workspace layout
    unsigned* hpre     = (unsigned*)d_ws;                       // 12.8 MB bf16 h, slice-major [4][N][8]
    unsigned* edge_sorted = (unsigned*)(hpre + (size_t)N_NODES * 32); // 6.4 MB (4B recs)
    int2*  coarse      = (int2*)(edge_sorted + N_EDGES);        // 12.8 MB (dead after s4)
    unsigned* h1bf     = (unsigned*)coarse;                     // alias: layer-1 out bf16 sliced
    int*   bh          = (int*)(coarse + N_EDGES);              // T2 ints
    int*   bh_ex       = bh + T2;
    int*   csum2       = bh_ex + T2;
    int*   coff2       = csum2 + NCH2;
    int*   row_ptr     = coff2 + NCH2;                          // 100001 ints
    short* wt1         = (short*)(row_ptr + N_NODES + 1);       // 16 KB
    short* wt2         = wt1 + 64 * 128;                        // 8 KB

    const int gemmBlocks = (N_NODES + 63) / 64;          // 1563
    const int gatherBlocks = (N_NODES * 64 + 255) / 256; // 25000

    // ---- two-level counting sort by dst (once; reused by both layers) + W prep ----
    s1_hist_prep<<<NBLK + 1, 256, 0, stream>>>(dst, bh, W1, W2, wt1, wt2);
    scan_sums<<<NCH2, 256, 0, stream>>>(bh, csum2, T2);
    scan_off<<<1, 512, 0, stream>>>(csum2, coff2, NCH2);
    scan_apply<<<NCH2, 256, 0, stream>>>(bh, coff2, bh_ex, T2);
    s3_scatter<<<NBLK, 256, 0, stream>>>(src, dst, mask, bh_ex, coarse);
    s4_fine<<<NBUCKET, 256, 0, stream>>>(coarse, bh_ex, edge_sorted, row_ptr);

    // ---- Layer 1: h1 = relu(A @ bf16(x@W1) + b1), stored bf16 sliced ----
    gemm_mfma<128, false><<<gemmBlocks, 256, 0, stream>>>(x, wt1, hpre);
    for (int p = 0; p < 4; ++p)
        gather_pass<true><<<gatherBlocks, 256, 0, stream>>>(hpre + (size_t)p * N_NODES * 8,
                                                            row_ptr, edge_sorted, b1, h1bf, p);

    // ---- Layer 2: h2 = relu(A @ bf16(h1@W2) + b2), fp32 out ----
    gemm_mfma<64, true><<<gemmBlocks, 256, 0, stream>>>(h1bf, wt2, hpre);
    for (int p = 0; p < 4; ++p)
        gather_pass<false><<<gatherBlocks, 256, 0, stream>>>(hpre + (size_t)p * N_NODES * 8,
                                                             row_ptr, edge_sorted, b2, out, p);
}

// Round 2
// 253.166 us; speedup vs baseline: 1.7537x; 1.7537x over previous
//
#include <hip/hip_runtime.h>
#include <hip/hip_bf16.h>

#define N_NODES 100000
#define N_EDGES 1600000
#define NBUCKET 391                 // ceil(100000 / 256) coarse buckets (dst >> 8)
#define NBLK 640                    // edge chunks (~2.5 blocks/CU)
#define CHUNK_E 2500                // 640 * 2500 = 1.6M exactly (div by 4 for int4)
#define CAP 4608                    // arena capacity per bucket (mean 4092 + 8 sigma)
#define GCSTRIDE 32                 // one counter per 128B line (avoid line contention)

typedef short v8s __attribute__((ext_vector_type(8)));
typedef float v4f __attribute__((ext_vector_type(4)));

static __device__ __forceinline__ unsigned pack_bf2(float a, float b) {
    __hip_bfloat162 p = __float22bfloat162_rn(make_float2(a, b));
    return *reinterpret_cast<unsigned*>(&p);
}
static __device__ __forceinline__ float2 bf2_to_f2(unsigned u) {
    __hip_bfloat162 p = *reinterpret_cast<__hip_bfloat162*>(&u);
    return __bfloat1622float2(p);
}

// ---------- shared GEMM tile body: out[node][32] bf162 = in[64 rows][K] @ W[K][64] ----------
// W is fp32 row-major [K][64]; staged transposed+packed to bf16 in LDS on the fly.
template<int K, bool IN_BF>
static __device__ __forceinline__ void gemm_tile(const void* __restrict__ in,
                                                 const float* __restrict__ W,
                                                 unsigned* __restrict__ outp,
                                                 int tile, unsigned* smem) {
    unsigned (*xs)[K / 2 + 4] = (unsigned(*)[K / 2 + 4])smem;
    unsigned (*ws)[K / 2 + 4] = (unsigned(*)[K / 2 + 4])(smem + 64 * (K / 2 + 4));
    const int t = threadIdx.x;
    const int row0 = tile * 64;
    // stage W: W[k][c] fp32 -> ws[c] bf16 at short index k (transpose via LDS short writes)
    {
        const float2* g2 = (const float2*)W;
        for (int i = t; i < 64 * K / 2; i += 256) {
            const float2 v = g2[i];
            const int k = (2 * i) >> 6;   // W row
            const int c = (2 * i) & 63;   // W col (pair c, c+1)
            ((short*)&ws[c][0])[k]     = (short)(pack_bf2(v.x, 0.f) & 0xFFFF);
            ((short*)&ws[c + 1][0])[k] = (short)(pack_bf2(v.y, 0.f) & 0xFFFF);
        }
    }
    if (IN_BF) {
        const uint2* g = (const uint2*)in;
        for (int i = t; i < 64 * K / 4; i += 256) {
            const int r = i / (K / 4), cu = i % (K / 4);
            const int row = row0 + r;
            uint2 v = make_uint2(0u, 0u);
            if (row < N_NODES) v = g[(size_t)row * (K / 4) + cu];
            ((uint2*)&xs[r][0])[cu] = v;
        }
    } else {
        const float4* g = (const float4*)in;
        for (int i = t; i < 64 * K / 4; i += 256) {
            const int r = i / (K / 4), cu = i % (K / 4);
            const int row = row0 + r;
            uint2 v = make_uint2(0u, 0u);
            if (row < N_NODES) {
                float4 f = g[(size_t)row * (K / 4) + cu];
                v.x = pack_bf2(f.x, f.y);
                v.y = pack_bf2(f.z, f.w);
            }
            ((uint2*)&xs[r][0])[cu] = v;
        }
    }
    __syncthreads();
    const int w = t >> 6;
    const int lane = t & 63;
    const int l15 = lane & 15;
    const int quad = lane >> 4;
    v4f acc[4];
#pragma unroll
    for (int tt = 0; tt < 4; ++tt) acc[tt] = (v4f){0.f, 0.f, 0.f, 0.f};
#pragma unroll
    for (int k0 = 0; k0 < K; k0 += 32) {
        const int ku = k0 / 2 + quad * 4;
        const v8s xb = *(const v8s*)&xs[w * 16 + l15][ku];   // B: n=node
#pragma unroll
        for (int tt = 0; tt < 4; ++tt) {
            const v8s wa = *(const v8s*)&ws[16 * tt + l15][ku];  // A: m=out col
            acc[tt] = __builtin_amdgcn_mfma_f32_16x16x32_bf16(wa, xb, acc[tt], 0, 0, 0);
        }
    }
    const int node = row0 + w * 16 + l15;
    if (node < N_NODES) {
#pragma unroll
        for (int tt = 0; tt < 4; ++tt) {
            uint2 o;
            o.x = pack_bf2(acc[tt][0], acc[tt][1]);
            o.y = pack_bf2(acc[tt][2], acc[tt][3]);
            *(uint2*)&outp[(size_t)node * 32 + 8 * tt + 2 * quad] = o;
        }
    }
}

// ---------- K1: blocks [0,NBLK) = two-pass bucket scatter; blocks >= NBLK = gemm1 tiles ----------
// Pass 1: LDS histogram of chunk. Reserve per-bucket arena ranges via padded global atomics.
// Pass 2: re-read chunk (L2-hot), place records into arena[bucket*CAP + offset].
__global__ __launch_bounds__(256) void k1_sort_gemm(const int* __restrict__ src,
                                                    const int* __restrict__ dst,
                                                    const float* __restrict__ wgt,
                                                    const float* __restrict__ x,
                                                    const float* __restrict__ W1,
                                                    int* __restrict__ gcount,
                                                    int2* __restrict__ arena,
                                                    unsigned* __restrict__ hpre) {
    __shared__ unsigned smem[2 * 64 * (128 / 2 + 4)];   // 34.8 KB (gemm K=128)
    __shared__ int hist[NBUCKET];
    __shared__ int cur[NBUCKET];
    const int b = blockIdx.x;
    if (b >= NBLK) {
        gemm_tile<128, false>(x, W1, hpre, b - NBLK, smem);
        return;
    }
    const int t = threadIdx.x;
    for (int i = t; i < NBUCKET; i += 256) hist[i] = 0;
    __syncthreads();
    const int4* d4 = (const int4*)(dst + b * CHUNK_E);
    for (int i = t; i < CHUNK_E / 4; i += 256) {
        const int4 v = d4[i];
        atomicAdd(&hist[v.x >> 8], 1);
        atomicAdd(&hist[v.y >> 8], 1);
        atomicAdd(&hist[v.z >> 8], 1);
        atomicAdd(&hist[v.w >> 8], 1);
    }
    __syncthreads();
    for (int i = t; i < NBUCKET; i += 256) {
        const int h = hist[i];
        const int base = (h > 0) ? atomicAdd(&gcount[i * GCSTRIDE], h) : 0;
        cur[i] = i * CAP + base;
    }
    __syncthreads();
    const int4*   s4p = (const int4*)(src + b * CHUNK_E);
    const float4* w4  = (const float4*)(wgt + b * CHUNK_E);
    for (int i = t; i < CHUNK_E / 4; i += 256) {
        const int4 sv = s4p[i];
        const int4 dv = d4[i];
        const float4 wv = w4[i];
        {
            const int pos = atomicAdd(&cur[dv.x >> 8], 1);
            arena[pos] = make_int2(sv.x | ((dv.x & 255) << 17), __float_as_int(wv.x));
        }
        {
            const int pos = atomicAdd(&cur[dv.y >> 8], 1);
            arena[pos] = make_int2(sv.y | ((dv.y & 255) << 17), __float_as_int(wv.y));
        }
        {
            const int pos = atomicAdd(&cur[dv.z >> 8], 1);
            arena[pos] = make_int2(sv.z | ((dv.z & 255) << 17), __float_as_int(wv.z));
        }
        {
            const int pos = atomicAdd(&cur[dv.w >> 8], 1);
            arena[pos] = make_int2(sv.w | ((dv.w & 255) << 17), __float_as_int(wv.w));
        }
    }
}

// ---------- gemm2 wrapper (K=64, bf16 input) ----------
__global__ __launch_bounds__(256) void gemm2_k(const unsigned* __restrict__ h1bf,
                                               const float* __restrict__ W2,
                                               unsigned* __restrict__ hpre) {
    __shared__ unsigned smem[2 * 64 * (64 / 2 + 4)];    // 18 KB
    gemm_tile<64, true>(h1bf, W2, hpre, blockIdx.x, smem);
}

// ---------- S4: per-bucket fine sort (256 nodes, 1 bin/thread) + row_ptr ----------
// Bucket base = sum of gcount[i<b] (L2-hot padded counters). record = src(17) | wq(15).
__global__ __launch_bounds__(256) void s4_fine(const int2* __restrict__ arena,
                                               const int* __restrict__ gcount,
                                               unsigned* __restrict__ edge_sorted,
                                               int* __restrict__ row_ptr) {
    __shared__ int hist[256];
    __shared__ int part[256];
    __shared__ int cursor[256];
    __shared__ int sb[2];
    const int b = blockIdx.x;
    const int t = threadIdx.x;
    // global base for this bucket: exclusive sum over earlier buckets
    int partial = 0;
    for (int i = t; i < b; i += 256) partial += gcount[i * GCSTRIDE];
    part[t] = partial;
    __syncthreads();
    for (int off = 128; off > 0; off >>= 1) {
        if (t < off) part[t] += part[t + off];
        __syncthreads();
    }
    if (t == 0) { sb[0] = part[0]; sb[1] = gcount[b * GCSTRIDE]; }
    __syncthreads();
    const int gbase = sb[0];
    const int cnt   = sb[1];
    const int abeg  = b * CAP;
    hist[t] = 0;
    __syncthreads();
    for (int i = t; i < cnt; i += 256)
        atomicAdd(&hist[(arena[abeg + i].x >> 17) & 255], 1);
    __syncthreads();
    const int v = hist[t];
    part[t] = v;
    __syncthreads();
    for (int off = 1; off < 256; off <<= 1) {
        int u = (t >= off) ? part[t - off] : 0;
        __syncthreads();
        part[t] += u;
        __syncthreads();
    }
    const int excl = gbase + part[t] - v;
    cursor[t] = excl;
    const int node = b * 256 + t;
    if (node < N_NODES) row_ptr[node] = excl;
    if (b == NBUCKET - 1 && t == 0) row_ptr[N_NODES] = N_EDGES;
    __syncthreads();
    for (int i = t; i < cnt; i += 256) {
        const int2 ev = arena[abeg + i];
        const int f = (ev.x >> 17) & 255;
        const int pos = atomicAdd(&cursor[f], 1);
        unsigned wq = (unsigned)__float2uint_rn(__int_as_float(ev.y) * 32767.f);
        wq = min(wq, 32767u);
        edge_sorted[pos] = (unsigned)(ev.x & 0x1FFFF) | (wq << 17);
    }
}

// ---------- Gather step: 8 edges, 8 lanes/edge, per-lane 4B edge rec + 16B h-load ----------
template<bool FULL>
static __device__ __forceinline__ void octo_step(const unsigned* __restrict__ h,
                                                 const unsigned* __restrict__ recs,
                                                 int e, int n, int q, int cg,
                                                 float acc[8]) {
    unsigned u;
    if (FULL) {
        u = recs[e + q];
    } else {
        u = recs[e + min(q, n - 1)];
    }
    const int sx = u & 0x1FFFF;
    float wq = (float)(u >> 17) * (1.f / 32767.f);
    if (!FULL) wq = (q < n) ? wq : 0.f;
    const uint4 hv = *(const uint4*)&h[(size_t)sx * 32 + cg * 4];
    const float2 f0 = bf2_to_f2(hv.x);
    const float2 f1 = bf2_to_f2(hv.y);
    const float2 f2 = bf2_to_f2(hv.z);
    const float2 f3 = bf2_to_f2(hv.w);
    acc[0] += wq * f0.x; acc[1] += wq * f0.y;
    acc[2] += wq * f1.x; acc[3] += wq * f1.y;
    acc[4] += wq * f2.x; acc[5] += wq * f2.y;
    acc[6] += wq * f3.x; acc[7] += wq * f3.y;
}

// ---------- Gather-aggregate (bf16 h): wave per node, 8 lanes per edge ----------
template<bool OUT_BF>
__global__ __launch_bounds__(256) void gather_octo(const unsigned* __restrict__ h, // bf162[N][32]
                                                   const int* __restrict__ row_ptr,
                                                   const unsigned* __restrict__ recs,
                                                   const float* __restrict__ bias,
                                                   void* __restrict__ outp) {
    const int node = (blockIdx.x * 256 + threadIdx.x) >> 6;
    if (node >= N_NODES) return;
    const int lane = threadIdx.x & 63;
    const int q  = lane >> 3;        // sub-wave: which of 8 edges
    const int cg = lane & 7;         // 16B chunk: cols 8*cg .. 8*cg+7
    const int beg = __builtin_amdgcn_readfirstlane(row_ptr[node]);
    const int end = __builtin_amdgcn_readfirstlane(row_ptr[node + 1]);
    float acc[8];
#pragma unroll
    for (int i = 0; i < 8; ++i) acc[i] = 0.f;
    int e = beg;
    for (; e + 16 <= end; e += 16) {           // 2 independent chains in flight
        octo_step<true>(h, recs, e, 8, q, cg, acc);
        octo_step<true>(h, recs, e + 8, 8, q, cg, acc);
    }
    if (e + 8 <= end) {
        octo_step<true>(h, recs, e, 8, q, cg, acc);
        e += 8;
    }
    if (e < end) {
        octo_step<false>(h, recs, e, end - e, q, cg, acc);
    }
    // stage 1: xor 8 (q bit0) — keep upper 4 accs if lane&8
    const bool h8 = (lane & 8) != 0;
    const float t0 = __shfl_xor(h8 ? acc[0] : acc[4], 8);
    const float t1 = __shfl_xor(h8 ? acc[1] : acc[5], 8);
    const float t2 = __shfl_xor(h8 ? acc[2] : acc[6], 8);
    const float t3 = __shfl_xor(h8 ? acc[3] : acc[7], 8);
    const float a0 = (h8 ? acc[4] : acc[0]) + t0;
    const float a1 = (h8 ? acc[5] : acc[1]) + t1;
    const float a2 = (h8 ? acc[6] : acc[2]) + t2;
    const float a3 = (h8 ? acc[7] : acc[3]) + t3;
    // stage 2: xor 16 (q bit1) — keep upper pair if lane&16
    const bool h16 = (lane & 16) != 0;
    const float u0 = __shfl_xor(h16 ? a0 : a2, 16);
    const float u1 = __shfl_xor(h16 ? a1 : a3, 16);
    const float b0 = (h16 ? a2 : a0) + u0;
    const float b1 = (h16 ? a3 : a1) + u1;
    // stage 3: xor 32 (q bit2) — keep upper if lane&32
    const bool h32 = (lane & 32) != 0;
    const float v0 = __shfl_xor(h32 ? b0 : b1, 32);
    const float rsum = (h32 ? b1 : b0) + v0;
    // lane holds col = 8*cg + (4*q0 + 2*q1 + q2)
    const int colq = ((q & 1) << 2) | (q & 2) | ((q >> 2) & 1);
    const int col = 8 * cg + colq;
    const float r = fmaxf(rsum + bias[col], 0.f);
    if (OUT_BF) {
        const unsigned p = pack_bf2(r, 0.f);
        ((short*)outp)[(size_t)node * 64 + col] = (short)(p & 0xFFFF);
    } else {
        ((float*)outp)[(size_t)node * 64 + col] = r;
    }
}

extern "C" void kernel_launch(void* const* d_in, const int* in_sizes, int n_in,
                              void* d_out, int out_size, void* d_ws, size_t ws_size,
                              hipStream_t stream) {
    const float* x    = (const float*)d_in[0];          // [100000, 128]
    const int*   eidx = (const int*)d_in[1];            // [2, 1600000]
    const float* mask = (const float*)d_in[2];          // [1600000]
    const float* W1   = (const float*)d_in[3];          // [128, 64]
    const float* b1   = (const float*)d_in[4];          // [64]
    const float* W2   = (const float*)d_in[5];          // [64, 64]
    const float* b2   = (const float*)d_in[6];          // [64]
    float* out = (float*)d_out;                          // [100000, 64]

    const int* src = eidx;
    const int* dst = eidx + N_EDGES;

    // workspace layout
    unsigned* hpre        = (unsigned*)d_ws;                           // 12.8 MB bf16 h [N][32]
    unsigned* edge_sorted = (unsigned*)(hpre + (size_t)N_NODES * 32);  // 6.4 MB (4B recs)
    int2*     arena       = (int2*)(edge_sorted + N_EDGES);            // 14.4 MB (dead after s4)
    unsigned* h1bf        = (unsigned*)arena;                          // alias: layer-1 out bf16
    int*      gcount      = (int*)(arena + (size_t)NBUCKET * CAP);     // 50 KB padded counters
    int*      row_ptr     = gcount + NBUCKET * GCSTRIDE;               // 100001 ints

    const int gemmBlocks = (N_NODES + 63) / 64;          // 1563
    const int gatherBlocks = (N_NODES * 64 + 255) / 256; // 25000

    // zero the padded bucket counters (1.5 KB of live data; stream-ordered, capturable)
    hipMemsetAsync(gcount, 0, NBUCKET * GCSTRIDE * sizeof(int), stream);

    // K1: bucket scatter (blocks 0..639) + layer-1 GEMM tiles (blocks 640..2202)
    k1_sort_gemm<<<NBLK + gemmBlocks, 256, 0, stream>>>(src, dst, mask, x, W1,
                                                        gcount, arena, hpre);
    // per-bucket fine sort -> edge_sorted + row_ptr
    s4_fine<<<NBUCKET, 256, 0, stream>>>(arena, gcount, edge_sorted, row_ptr);

    // Layer 1 aggregate: h1 = relu(A @ hpre + b1), stored bf16 [N][32] bf162
    gather_octo<true><<<gatherBlocks, 256, 0, stream>>>(hpre, row_ptr, edge_sorted,
                                                        b1, h1bf);
    // Layer 2 GEMM + aggregate
    gemm2_k<<<gemmBlocks, 256, 0, stream>>>(h1bf, W2, hpre);
    gather_octo<false><<<gatherBlocks, 256, 0, stream>>>(hpre, row_ptr, edge_sorted,
                                                         b2, out);
}

// Round 3
// 239.011 us; speedup vs baseline: 1.8576x; 1.0592x over previous
//
#include <hip/hip_runtime.h>
#include <hip/hip_bf16.h>

#define N_NODES 100000
#define N_EDGES 1600000
#define NBUCKET 391                 // ceil(100000 / 256) coarse buckets (dst >> 8)
#define NBLK 640                    // edge chunks
#define CHUNK_E 2500                // 640 * 2500 = 1.6M exactly (div by 4 for int4)
#define CAP 4608                    // arena capacity per bucket (mean 4092 + 8 sigma)
#define GCSTRIDE 32                 // one counter per 128B line (avoid line contention)

typedef short v8s __attribute__((ext_vector_type(8)));
typedef float v4f __attribute__((ext_vector_type(4)));

static __device__ __forceinline__ unsigned pack_bf2(float a, float b) {
    __hip_bfloat162 p = __float22bfloat162_rn(make_float2(a, b));
    return *reinterpret_cast<unsigned*>(&p);
}
static __device__ __forceinline__ float2 bf2_to_f2(unsigned u) {
    __hip_bfloat162 p = *reinterpret_cast<__hip_bfloat162*>(&u);
    return __bfloat1622float2(p);
}

// ---------- K1 (1024 threads): blocks [0,NBLK) = LDS-ordered bucket scatter;
//                               blocks >= NBLK  = layer-1 GEMM tiles (16-wave mapping) ----------
__global__ __launch_bounds__(1024) void k1_sort_gemm(const int* __restrict__ src,
                                                     const int* __restrict__ dst,
                                                     const float* __restrict__ wgt,
                                                     const float* __restrict__ x,
                                                     const float* __restrict__ W1,
                                                     int* __restrict__ gcount,
                                                     int2* __restrict__ arena,
                                                     unsigned* __restrict__ hpre) {
    __shared__ unsigned smem[9216];   // 36.9 KB, shared by both paths
    const int b = blockIdx.x;
    const int t = threadIdx.x;

    if (b >= NBLK) {
        // ---- layer-1 GEMM tile: hpre[64 nodes][64 cols bf16] = x_tile @ W1 ----
        unsigned (*xs)[68] = (unsigned(*)[68])smem;            // 64 x (128/2+4)
        unsigned (*ws)[68] = (unsigned(*)[68])(smem + 64 * 68);
        const int tile = b - NBLK;
        const int row0 = tile * 64;
        {   // stage W1: fp32 [128][64] -> ws[col] bf16 at short index k (transpose)
            const float2* g2 = (const float2*)W1;
            for (int i = t; i < 64 * 128 / 2; i += 1024) {
                const float2 v = g2[i];
                const int k = (2 * i) >> 6;
                const int c = (2 * i) & 63;
                ((short*)&ws[c][0])[k]     = (short)(pack_bf2(v.x, 0.f) & 0xFFFF);
                ((short*)&ws[c + 1][0])[k] = (short)(pack_bf2(v.y, 0.f) & 0xFFFF);
            }
        }
        {   // stage x tile: fp32 -> bf16 packed
            const float4* g = (const float4*)x;
            for (int i = t; i < 64 * 32; i += 1024) {
                const int r = i >> 5, cu = i & 31;
                const int row = row0 + r;
                uint2 v = make_uint2(0u, 0u);
                if (row < N_NODES) {
                    float4 f = g[(size_t)row * 32 + cu];
                    v.x = pack_bf2(f.x, f.y);
                    v.y = pack_bf2(f.z, f.w);
                }
                ((uint2*)&xs[r][0])[cu] = v;
            }
        }
        __syncthreads();
        const int w = t >> 6, lane = t & 63;
        const int l15 = lane & 15, quad = lane >> 4;
        const int a = w & 3;       // out-col group (16 cols)
        const int g_ = w >> 2;     // node group (16 nodes)
        v4f acc = (v4f){0.f, 0.f, 0.f, 0.f};
#pragma unroll
        for (int k0 = 0; k0 < 128; k0 += 32) {
            const int ku = k0 / 2 + quad * 4;
            const v8s xb = *(const v8s*)&xs[g_ * 16 + l15][ku];
            const v8s wa = *(const v8s*)&ws[16 * a + l15][ku];
            acc = __builtin_amdgcn_mfma_f32_16x16x32_bf16(wa, xb, acc, 0, 0, 0);
        }
        const int node = row0 + g_ * 16 + l15;
        if (node < N_NODES) {
            uint2 o;
            o.x = pack_bf2(acc[0], acc[1]);
            o.y = pack_bf2(acc[2], acc[3]);
            *(uint2*)&hpre[(size_t)node * 32 + 8 * a + 2 * quad] = o;
        }
        return;
    }

    // ---- sort path: block-local counting sort of 2500 edges, coalesced arena writes ----
    int*  hist = (int*)smem;            // [391]
    int*  part = (int*)smem + 400;      // [512]
    int*  lcur = (int*)smem + 912;      // [391] local cursor (init = exclusive scan)
    int*  tgb  = (int*)smem + 1304;     // [391] global target base - local base
    int2* ord  = (int2*)((int*)smem + 1696); // [2500] bucket-ordered records
    int*  tg   = (int*)smem + 1696 + 5000;   // [2500] global targets

    for (int i = t; i < NBUCKET; i += 1024) hist[i] = 0;
    __syncthreads();
    const int4* d4 = (const int4*)(dst + b * CHUNK_E);
    for (int i = t; i < CHUNK_E / 4; i += 1024) {
        const int4 v = d4[i];
        atomicAdd(&hist[v.x >> 8], 1);
        atomicAdd(&hist[v.y >> 8], 1);
        atomicAdd(&hist[v.z >> 8], 1);
        atomicAdd(&hist[v.w >> 8], 1);
    }
    __syncthreads();
    // exclusive scan over 391 bins (Hillis-Steele on 512, guarded; barriers block-wide)
    if (t < 512) part[t] = (t < NBUCKET) ? hist[t] : 0;
    __syncthreads();
    for (int off = 1; off < 512; off <<= 1) {
        int u = 0;
        if (t < 512 && t >= off) u = part[t - off];
        __syncthreads();
        if (t < 512) part[t] += u;
        __syncthreads();
    }
    if (t < NBUCKET) {
        const int hv = hist[t];
        const int lbase = part[t] - hv;          // exclusive
        lcur[t] = lbase;
        int grsv = 0;
        if (hv > 0) grsv = atomicAdd(&gcount[t * GCSTRIDE], hv);
        tgb[t] = t * CAP + grsv - lbase;
    }
    __syncthreads();
    // local scatter into LDS (records ordered by bucket) + per-record global target
    const int4*   s4p = (const int4*)(src + b * CHUNK_E);
    const float4* w4  = (const float4*)(wgt + b * CHUNK_E);
    for (int i = t; i < CHUNK_E / 4; i += 1024) {
        const int4 sv = s4p[i];
        const int4 dv = d4[i];
        const float4 wv = w4[i];
        {
            const int bk = dv.x >> 8;
            const int lp = atomicAdd(&lcur[bk], 1);
            ord[lp] = make_int2(sv.x | ((dv.x & 255) << 17), __float_as_int(wv.x));
            tg[lp] = tgb[bk] + lp;
        }
        {
            const int bk = dv.y >> 8;
            const int lp = atomicAdd(&lcur[bk], 1);
            ord[lp] = make_int2(sv.y | ((dv.y & 255) << 17), __float_as_int(wv.y));
            tg[lp] = tgb[bk] + lp;
        }
        {
            const int bk = dv.z >> 8;
            const int lp = atomicAdd(&lcur[bk], 1);
            ord[lp] = make_int2(sv.z | ((dv.z & 255) << 17), __float_as_int(wv.z));
            tg[lp] = tgb[bk] + lp;
        }
        {
            const int bk = dv.w >> 8;
            const int lp = atomicAdd(&lcur[bk], 1);
            ord[lp] = make_int2(sv.w | ((dv.w & 255) << 17), __float_as_int(wv.w));
            tg[lp] = tgb[bk] + lp;
        }
    }
    __syncthreads();
    // linear write-out: consecutive threads -> consecutive addresses within bucket runs
    for (int i = t; i < CHUNK_E; i += 1024) {
        arena[tg[i]] = ord[i];
    }
}

// ---------- gemm2 (256 threads): h2pre = bf16(h1 @ W2), input bf16 [N][64] ----------
__global__ __launch_bounds__(256) void gemm2_k(const unsigned* __restrict__ in,
                                               const float* __restrict__ W2,
                                               unsigned* __restrict__ outp) {
    __shared__ unsigned smem[2 * 64 * 36];   // xs/ws 64 x (64/2+4)
    unsigned (*xs)[36] = (unsigned(*)[36])smem;
    unsigned (*ws)[36] = (unsigned(*)[36])(smem + 64 * 36);
    const int t = threadIdx.x;
    const int row0 = blockIdx.x * 64;
    {
        const float2* g2 = (const float2*)W2;
        for (int i = t; i < 64 * 64 / 2; i += 256) {
            const float2 v = g2[i];
            const int k = (2 * i) >> 6;
            const int c = (2 * i) & 63;
            ((short*)&ws[c][0])[k]     = (short)(pack_bf2(v.x, 0.f) & 0xFFFF);
            ((short*)&ws[c + 1][0])[k] = (short)(pack_bf2(v.y, 0.f) & 0xFFFF);
        }
    }
    {
        const uint2* g = (const uint2*)in;
        for (int i = t; i < 64 * 16; i += 256) {
            const int r = i >> 4, cu = i & 15;
            const int row = row0 + r;
            uint2 v = make_uint2(0u, 0u);
            if (row < N_NODES) v = g[(size_t)row * 16 + cu];
            ((uint2*)&xs[r][0])[cu] = v;
        }
    }
    __syncthreads();
    const int w = t >> 6, lane = t & 63;
    const int l15 = lane & 15, quad = lane >> 4;
    v4f acc[4];
#pragma unroll
    for (int tt = 0; tt < 4; ++tt) acc[tt] = (v4f){0.f, 0.f, 0.f, 0.f};
#pragma unroll
    for (int k0 = 0; k0 < 64; k0 += 32) {
        const int ku = k0 / 2 + quad * 4;
        const v8s xb = *(const v8s*)&xs[w * 16 + l15][ku];
#pragma unroll
        for (int tt = 0; tt < 4; ++tt) {
            const v8s wa = *(const v8s*)&ws[16 * tt + l15][ku];
            acc[tt] = __builtin_amdgcn_mfma_f32_16x16x32_bf16(wa, xb, acc[tt], 0, 0, 0);
        }
    }
    const int node = row0 + w * 16 + l15;
    if (node < N_NODES) {
#pragma unroll
        for (int tt = 0; tt < 4; ++tt) {
            uint2 o;
            o.x = pack_bf2(acc[tt][0], acc[tt][1]);
            o.y = pack_bf2(acc[tt][2], acc[tt][3]);
            *(uint2*)&outp[(size_t)node * 32 + 8 * tt + 2 * quad] = o;
        }
    }
}

// ---------- S4 (1024 threads): per-bucket fine sort (256 nodes) + row_ptr ----------
__global__ __launch_bounds__(1024) void s4_fine(const int2* __restrict__ arena,
                                                const int* __restrict__ gcount,
                                                unsigned* __restrict__ edge_sorted,
                                                int* __restrict__ row_ptr) {
    __shared__ int red[1024];
    __shared__ int hist[256];
    __shared__ int part[256];
    __shared__ int cursor[256];
    const int b = blockIdx.x;
    const int t = threadIdx.x;
    // bucket global base = exclusive sum of earlier buckets' counts
    int partial = 0;
    for (int i = t; i < b; i += 1024) partial += gcount[i * GCSTRIDE];
    red[t] = partial;
    __syncthreads();
    for (int off = 512; off > 0; off >>= 1) {
        if (t < off) red[t] += red[t + off];
        __syncthreads();
    }
    const int gbase = red[0];
    const int cnt   = gcount[b * GCSTRIDE];
    const int abeg  = b * CAP;
    if (t < 256) hist[t] = 0;
    __syncthreads();
    for (int i = t; i < cnt; i += 1024)
        atomicAdd(&hist[(arena[abeg + i].x >> 17) & 255], 1);
    __syncthreads();
    const int v = (t < 256) ? hist[t] : 0;
    if (t < 256) part[t] = v;
    __syncthreads();
    for (int off = 1; off < 256; off <<= 1) {
        int u = 0;
        if (t < 256 && t >= off) u = part[t - off];
        __syncthreads();
        if (t < 256) part[t] += u;
        __syncthreads();
    }
    if (t < 256) {
        const int excl = gbase + part[t] - v;
        cursor[t] = excl;
        const int node = b * 256 + t;
        if (node < N_NODES) row_ptr[node] = excl;
    }
    if (b == NBUCKET - 1 && t == 0) row_ptr[N_NODES] = N_EDGES;
    __syncthreads();
    for (int i = t; i < cnt; i += 1024) {
        const int2 ev = arena[abeg + i];
        const int f = (ev.x >> 17) & 255;
        const int pos = atomicAdd(&cursor[f], 1);
        unsigned wq = (unsigned)__float2uint_rn(__int_as_float(ev.y) * 32767.f);
        wq = min(wq, 32767u);
        edge_sorted[pos] = (unsigned)(ev.x & 0x1FFFF) | (wq << 17);
    }
}

// ---------- Gather step: 8 edges, 8 lanes/edge, per-lane 4B edge rec + 16B h-load ----------
template<bool FULL>
static __device__ __forceinline__ void octo_step(const unsigned* __restrict__ h,
                                                 const unsigned* __restrict__ recs,
                                                 int e, int n, int q, int cg,
                                                 float acc[8]) {
    unsigned u;
    if (FULL) {
        u = recs[e + q];
    } else {
        u = recs[e + min(q, n - 1)];
    }
    const int sx = u & 0x1FFFF;
    float wq = (float)(u >> 17) * (1.f / 32767.f);
    if (!FULL) wq = (q < n) ? wq : 0.f;
    const uint4 hv = *(const uint4*)&h[(size_t)sx * 32 + cg * 4];
    const float2 f0 = bf2_to_f2(hv.x);
    const float2 f1 = bf2_to_f2(hv.y);
    const float2 f2 = bf2_to_f2(hv.z);
    const float2 f3 = bf2_to_f2(hv.w);
    acc[0] += wq * f0.x; acc[1] += wq * f0.y;
    acc[2] += wq * f1.x; acc[3] += wq * f1.y;
    acc[4] += wq * f2.x; acc[5] += wq * f2.y;
    acc[6] += wq * f3.x; acc[7] += wq * f3.y;
}

// ---------- Gather-aggregate (bf16 h): wave per node, 8 lanes per edge ----------
template<bool OUT_BF>
__global__ __launch_bounds__(256) void gather_octo(const unsigned* __restrict__ h, // bf162[N][32]
                                                   const int* __restrict__ row_ptr,
                                                   const unsigned* __restrict__ recs,
                                                   const float* __restrict__ bias,
                                                   void* __restrict__ outp) {
    const int node = (blockIdx.x * 256 + threadIdx.x) >> 6;
    if (node >= N_NODES) return;
    const int lane = threadIdx.x & 63;
    const int q  = lane >> 3;        // sub-wave: which of 8 edges
    const int cg = lane & 7;         // 16B chunk: cols 8*cg .. 8*cg+7
    const int beg = __builtin_amdgcn_readfirstlane(row_ptr[node]);
    const int end = __builtin_amdgcn_readfirstlane(row_ptr[node + 1]);
    float acc[8];
#pragma unroll
    for (int i = 0; i < 8; ++i) acc[i] = 0.f;
    int e = beg;
    for (; e + 16 <= end; e += 16) {           // 2 independent chains in flight
        octo_step<true>(h, recs, e, 8, q, cg, acc);
        octo_step<true>(h, recs, e + 8, 8, q, cg, acc);
    }
    if (e + 8 <= end) {
        octo_step<true>(h, recs, e, 8, q, cg, acc);
        e += 8;
    }
    if (e < end) {
        octo_step<false>(h, recs, e, end - e, q, cg, acc);
    }
    // stage 1: xor 8 (q bit0) — keep upper 4 accs if lane&8
    const bool h8 = (lane & 8) != 0;
    const float t0 = __shfl_xor(h8 ? acc[0] : acc[4], 8);
    const float t1 = __shfl_xor(h8 ? acc[1] : acc[5], 8);
    const float t2 = __shfl_xor(h8 ? acc[2] : acc[6], 8);
    const float t3 = __shfl_xor(h8 ? acc[3] : acc[7], 8);
    const float a0 = (h8 ? acc[4] : acc[0]) + t0;
    const float a1 = (h8 ? acc[5] : acc[1]) + t1;
    const float a2 = (h8 ? acc[6] : acc[2]) + t2;
    const float a3 = (h8 ? acc[7] : acc[3]) + t3;
    // stage 2: xor 16 (q bit1) — keep upper pair if lane&16
    const bool h16 = (lane & 16) != 0;
    const float u0 = __shfl_xor(h16 ? a0 : a2, 16);
    const float u1 = __shfl_xor(h16 ? a1 : a3, 16);
    const float b0 = (h16 ? a2 : a0) + u0;
    const float b1 = (h16 ? a3 : a1) + u1;
    // stage 3: xor 32 (q bit2) — keep upper if lane&32
    const bool h32 = (lane & 32) != 0;
    const float v0 = __shfl_xor(h32 ? b0 : b1, 32);
    const float rsum = (h32 ? b1 : b0) + v0;
    // lane holds col = 8*cg + (4*q0 + 2*q1 + q2)
    const int colq = ((q & 1) << 2) | (q & 2) | ((q >> 2) & 1);
    const int col = 8 * cg + colq;
    const float r = fmaxf(rsum + bias[col], 0.f);
    if (OUT_BF) {
        const unsigned p = pack_bf2(r, 0.f);
        ((short*)outp)[(size_t)node * 64 + col] = (short)(p & 0xFFFF);
    } else {
        ((float*)outp)[(size_t)node * 64 + col] = r;
    }
}

extern "C" void kernel_launch(void* const* d_in, const int* in_sizes, int n_in,
                              void* d_out, int out_size, void* d_ws, size_t ws_size,
                              hipStream_t stream) {
    const float* x    = (const float*)d_in[0];          // [100000, 128]
    const int*   eidx = (const int*)d_in[1];            // [2, 1600000]
    const float* mask = (const float*)d_in[2];          // [1600000]
    const float* W1   = (const float*)d_in[3];          // [128, 64]
    const float* b1   = (const float*)d_in[4];          // [64]
    const float* W2   = (const float*)d_in[5];          // [64, 64]
    const float* b2   = (const float*)d_in[6];          // [64]
    float* out = (float*)d_out;                          // [100000, 64]

    const int* src = eidx;
    const int* dst = eidx + N_EDGES;

    // workspace layout
    unsigned* hpre        = (unsigned*)d_ws;                           // 12.8 MB bf16 h [N][32]
    unsigned* edge_sorted = (unsigned*)(hpre + (size_t)N_NODES * 32);  // 6.4 MB (4B recs)
    int2*     arena       = (int2*)(edge_sorted + N_EDGES);            // 14.4 MB (dead after s4)
    unsigned* h1bf        = (unsigned*)arena;                          // alias: layer-1 out bf16
    int*      gcount      = (int*)(arena + (size_t)NBUCKET * CAP);     // 50 KB padded counters
    int*      row_ptr     = gcount + NBUCKET * GCSTRIDE;               // 100001 ints

    const int gemmBlocks = (N_NODES + 63) / 64;          // 1563
    const int gatherBlocks = (N_NODES * 64 + 255) / 256; // 25000

    // zero the padded bucket counters (stream-ordered, graph-capturable)
    hipMemsetAsync(gcount, 0, NBUCKET * GCSTRIDE * sizeof(int), stream);

    // K1: bucket scatter (blocks 0..639, 16 waves each) + layer-1 GEMM tiles
    k1_sort_gemm<<<NBLK + gemmBlocks, 1024, 0, stream>>>(src, dst, mask, x, W1,
                                                         gcount, arena, hpre);
    // per-bucket fine sort -> edge_sorted + row_ptr
    s4_fine<<<NBUCKET, 1024, 0, stream>>>(arena, gcount, edge_sorted, row_ptr);

    // Layer 1 aggregate: h1 = relu(A @ hpre + b1), stored bf16 [N][64]
    gather_octo<true><<<gatherBlocks, 256, 0, stream>>>(hpre, row_ptr, edge_sorted,
                                                        b1, h1bf);
    // Layer 2 GEMM + aggregate
    gemm2_k<<<gemmBlocks, 256, 0, stream>>>(h1bf, W2, hpre);
    gather_octo<false><<<gatherBlocks, 256, 0, stream>>>(hpre, row_ptr, edge_sorted,
                                                         b2, out);
}